// Round 4
// baseline (345.497 us; speedup 1.0000x reference)
//
#include <hip/hip_runtime.h>

#define NBINS 128
#define NB2   (NBINS * NBINS)
#define TPB   1024
#define NBLK  256
#define RAD   4
#define TAPS  (2 * RAD + 1)
#define MAXPART 64
#define TPB2  256

// Kernel 1: per-block 64KB LDS fp32 histogram of truncated (+-4 sigma, 9x9)
// Gaussian KDE taps. 1 block/CU (66KB LDS), 16 waves/CU.
// LDS accumulate MUST lower to native ds_add_f32 (no-return, workgroup scope,
// relaxed) -- R3's unsafeAtomicAdd on a generic pointer took a flat-atomic
// path: 222us at 2% VALUBusy.
__global__ __launch_bounds__(TPB, 4) void kde_hist_kernel(
    const float* __restrict__ x,
    const float* __restrict__ ex,
    const float* __restrict__ ey,
    float* __restrict__ ws_total,
    float* __restrict__ partials,
    int n, int npart)
{
    __shared__ float h[NB2];
    __shared__ float red[TPB / 64];

    float4* h4 = (float4*)h;
    for (int i = threadIdx.x; i < NB2 / 4; i += TPB)
        h4[i] = make_float4(0.f, 0.f, 0.f, 0.f);

    const float lox = ex[0];
    const float bwx = ex[1] - ex[0];
    const float loy = ey[0];
    const float bwy = ey[1] - ey[0];
    const float ibx = 1.0f / bwx, iby = 1.0f / bwy;

    __syncthreads();

    float tsum = 0.f;
    const int stride = (int)gridDim.x * TPB;
    for (int p = (int)blockIdx.x * TPB + (int)threadIdx.x; p < n; p += stride) {
        // row p: cols 0,1 adjacent; 24B row stride -> naturally aligned 8B load
        const float2 xy = *(const float2*)(x + (size_t)p * 6);
        // t_i = (x - c_i)/bw = u - i with u = (x-lo)/bw - 0.5 (sigma units,
        // since bandwidth == bin width)
        const float u = (xy.x - lox) * ibx - 0.5f;
        const float v = (xy.y - loy) * iby - 0.5f;
        int ic = (int)floorf(u) - RAD;
        int jc = (int)floorf(v) - RAD;
        // clamp 9-tap window into grid; weights use the TRUE center, so a
        // clamped window just evaluates valid (tiny) far-tail weights at the
        // nearest in-grid bins -- exactly the bins the reference includes.
        ic = min(max(ic, 0), NBINS - TAPS);
        jc = min(max(jc, 0), NBINS - TAPS);

        float wx[TAPS], wy[TAPS];
        float sx = 0.f, sy = 0.f;
        #pragma unroll
        for (int k = 0; k < TAPS; ++k) {
            const float t = u - (float)(ic + k);
            const float w = __expf(-0.5f * t * t);
            wx[k] = w; sx += w;
            const float s = v - (float)(jc + k);
            const float w2 = __expf(-0.5f * s * s);
            wy[k] = w2; sy += w2;
        }
        tsum += sx * sy;  // exact sum of everything this point adds to h

        const int base = ic * NBINS + jc;
        #pragma unroll
        for (int a = 0; a < TAPS; ++a) {
            #pragma unroll
            for (int b = 0; b < TAPS; ++b) {
                // native LDS fp32 atomic add, result unused -> ds_add_f32
                __hip_atomic_fetch_add(&h[base + a * NBINS + b], wx[a] * wy[b],
                                       __ATOMIC_RELAXED,
                                       __HIP_MEMORY_SCOPE_WORKGROUP);
            }
        }
    }

    // block-reduce tsum -> one device atomic per block
    #pragma unroll
    for (int off = 32; off > 0; off >>= 1) tsum += __shfl_down(tsum, off, 64);
    if ((threadIdx.x & 63) == 0) red[threadIdx.x >> 6] = tsum;
    __syncthreads();

    // merge LDS hist into ws partials: private vectorized stores if one copy
    // per block fits, else device-atomic into pre-zeroed shared copies
    float* dst = partials + (size_t)((int)blockIdx.x % npart) * NB2;
    if (npart == (int)gridDim.x) {
        float4* d4 = (float4*)dst;
        for (int i = threadIdx.x; i < NB2 / 4; i += TPB) d4[i] = h4[i];
    } else {
        for (int i = threadIdx.x; i < NB2; i += TPB) unsafeAtomicAdd(dst + i, h[i]);
    }

    if (threadIdx.x == 0) {
        float s = 0.f;
        #pragma unroll
        for (int w = 0; w < TPB / 64; ++w) s += red[w];
        unsafeAtomicAdd(ws_total, s);
    }
}

// Kernel 2: reduce partials, normalize to density, emit fp32.
// Thread-per-output-element: 64 blocks (R3's 16-block float4 version was
// latency-bound and ate ~77us).
__global__ __launch_bounds__(TPB2) void kde_final_kernel(
    const float* __restrict__ partials,
    const float* __restrict__ ws_total,
    const float* __restrict__ ex,
    const float* __restrict__ ey,
    float* __restrict__ out,
    int npart)
{
    const int q = (int)blockIdx.x * TPB2 + (int)threadIdx.x;
    float acc = 0.f;
    for (int p = 0; p < npart; ++p)
        acc += partials[(size_t)p * NB2 + q];
    const float bwx = ex[1] - ex[0];
    const float bwy = ey[1] - ey[0];
    const float inv = 1.0f / (ws_total[0] * bwx * bwy);
    out[q] = acc * inv;
}

extern "C" void kernel_launch(void* const* d_in, const int* in_sizes, int n_in,
                              void* d_out, int out_size, void* d_ws, size_t ws_size,
                              hipStream_t stream)
{
    const float* x  = (const float*)d_in[0];
    const float* ex = (const float*)d_in[1];
    const float* ey = (const float*)d_in[2];
    float* out = (float*)d_out;
    const int n = in_sizes[0] / 6;

    float* ws_total = (float*)d_ws;                   // ws[0]: grand total
    float* partials = (float*)((char*)d_ws + 64);     // 64B-aligned partials

    // prefer one private 64KB copy per block (plain stores, no atomics);
    // else cap at MAXPART pre-zeroed copies merged with device atomics
    size_t fit = (ws_size > 64) ? (ws_size - 64) / (sizeof(float) * NB2) : 0;
    int npart;
    bool priv = (fit >= (size_t)NBLK);
    if (priv) npart = NBLK;
    else {
        npart = (int)((fit < (size_t)MAXPART) ? fit : (size_t)MAXPART);
        if (npart < 1) npart = 1;  // requires ws_size >= ~66KB
    }

    const size_t zero_bytes = priv ? 64 : 64 + (size_t)npart * NB2 * sizeof(float);
    hipMemsetAsync(d_ws, 0, zero_bytes, stream);

    kde_hist_kernel<<<NBLK, TPB, 0, stream>>>(x, ex, ey, ws_total, partials, n, npart);
    kde_final_kernel<<<NB2 / TPB2, TPB2, 0, stream>>>(partials, ws_total, ex, ey, out, npart);
}

// Round 5
// 286.825 us; speedup vs baseline: 1.2046x; 1.2046x over previous
//
#include <hip/hip_runtime.h>

#define NBINS 128
#define NB2   (NBINS * NBINS)
#define TPB   1024
#define NBLK  256
#define RAD   4
#define TAPS  (2 * RAD + 1)
#define TPB2  256

// Kernel 1: per-block 64KB LDS fp32 histogram of truncated (+-4 sigma, 9x9)
// Gaussian KDE taps. 256 blocks x 1024 thr = 1 block/CU, 16 waves.
// Atomic is unsafeAtomicAdd on a DIRECT array index (addrspace(3) provable)
// -> must emit native no-return ds_add_f32. R3 (hoisted generic float*) and
// R4 (__hip_atomic_fetch_add) both plateaued at ~220us / 3.3cyc per
// lane-atomic with SQ_LDS_BANK_CONFLICT == 0: flat-atomic / CAS lowering.
__global__ __launch_bounds__(TPB, 4) void kde_hist_kernel(
    const float* __restrict__ x,
    const float* __restrict__ ex,
    const float* __restrict__ ey,
    float* __restrict__ ws_total,
    float* __restrict__ partials,
    int n)
{
    __shared__ float h[NB2];
    __shared__ float red[TPB / 64];

    float4* h4 = (float4*)h;
    for (int i = threadIdx.x; i < NB2 / 4; i += TPB)
        h4[i] = make_float4(0.f, 0.f, 0.f, 0.f);

    const float lox = ex[0];
    const float bwx = ex[1] - ex[0];
    const float loy = ey[0];
    const float bwy = ey[1] - ey[0];
    const float ibx = 1.0f / bwx, iby = 1.0f / bwy;

    __syncthreads();

    float tsum = 0.f;
    const int stride = (int)gridDim.x * TPB;
    for (int p = (int)blockIdx.x * TPB + (int)threadIdx.x; p < n; p += stride) {
        // row p: cols 0,1 adjacent; 24B row stride -> naturally aligned 8B load
        const float2 xy = *(const float2*)(x + (size_t)p * 6);
        // t_i = (x - c_i)/bw = u - i with u = (x-lo)/bw - 0.5 (sigma units,
        // since bandwidth == bin width)
        const float u = (xy.x - lox) * ibx - 0.5f;
        const float v = (xy.y - loy) * iby - 0.5f;
        int ic = (int)floorf(u) - RAD;
        int jc = (int)floorf(v) - RAD;
        // clamp 9-tap window into grid; weights use the TRUE center, so a
        // clamped window evaluates valid (tiny) far-tail weights at the
        // nearest in-grid bins -- exactly the bins the reference includes.
        ic = min(max(ic, 0), NBINS - TAPS);
        jc = min(max(jc, 0), NBINS - TAPS);

        float wx[TAPS], wy[TAPS];
        float sx = 0.f, sy = 0.f;
        #pragma unroll
        for (int k = 0; k < TAPS; ++k) {
            const float t = u - (float)(ic + k);
            const float w = __expf(-0.5f * t * t);
            wx[k] = w; sx += w;
            const float s = v - (float)(jc + k);
            const float w2 = __expf(-0.5f * s * s);
            wy[k] = w2; sy += w2;
        }
        tsum += sx * sy;  // exact sum of everything this point adds to h

        const int base = ic * NBINS + jc;
        #pragma unroll
        for (int a = 0; a < TAPS; ++a) {
            #pragma unroll
            for (int b = 0; b < TAPS; ++b) {
                // direct indexed form: addrspace(3) inference -> ds_add_f32
                unsafeAtomicAdd(&h[base + a * NBINS + b], wx[a] * wy[b]);
            }
        }
    }

    // block-reduce tsum -> one device atomic per block
    #pragma unroll
    for (int off = 32; off > 0; off >>= 1) tsum += __shfl_down(tsum, off, 64);
    if ((threadIdx.x & 63) == 0) red[threadIdx.x >> 6] = tsum;
    __syncthreads();

    // private per-block partial copy: plain vectorized stores (ws is large
    // enough: R4's WRITE_SIZE showed the 16.8MB priv path ran)
    float4* d4 = (float4*)(partials + (size_t)blockIdx.x * NB2);
    for (int i = threadIdx.x; i < NB2 / 4; i += TPB) d4[i] = h4[i];

    if (threadIdx.x == 0) {
        float s = 0.f;
        #pragma unroll
        for (int w = 0; w < TPB / 64; ++w) s += red[w];
        unsafeAtomicAdd(ws_total, s);
    }
}

// Kernel 2: reduce 256 partial copies -> normalized density.
// 256 blocks; block owns 64 bins. Threads = [4 part-groups x 64 bins]:
// lane-consecutive bins -> coalesced 256B wave loads; each thread sums 64
// parts; 4-way LDS reduce. (R4's version walked all parts from few blocks:
// ~128us latency-bound.)
__global__ __launch_bounds__(TPB2) void kde_final_kernel(
    const float* __restrict__ partials,
    const float* __restrict__ ws_total,
    const float* __restrict__ ex,
    const float* __restrict__ ey,
    float* __restrict__ out)
{
    __shared__ float red[TPB2];
    const int bin = (int)blockIdx.x * 64 + ((int)threadIdx.x & 63);
    const int grp = (int)threadIdx.x >> 6;  // 0..3

    float acc = 0.f;
    #pragma unroll 8
    for (int p = grp * 64; p < grp * 64 + 64; ++p)
        acc += partials[(size_t)p * NB2 + bin];
    red[threadIdx.x] = acc;
    __syncthreads();

    if (threadIdx.x < 64) {
        const float bwx = ex[1] - ex[0];
        const float bwy = ey[1] - ey[0];
        const float inv = 1.0f / (ws_total[0] * bwx * bwy);
        const float tot = red[threadIdx.x] + red[64 + threadIdx.x] +
                          red[128 + threadIdx.x] + red[192 + threadIdx.x];
        out[bin] = tot * inv;
    }
}

extern "C" void kernel_launch(void* const* d_in, const int* in_sizes, int n_in,
                              void* d_out, int out_size, void* d_ws, size_t ws_size,
                              hipStream_t stream)
{
    const float* x  = (const float*)d_in[0];
    const float* ex = (const float*)d_in[1];
    const float* ey = (const float*)d_in[2];
    float* out = (float*)d_out;
    const int n = in_sizes[0] / 6;

    float* ws_total = (float*)d_ws;                   // ws[0]: grand total
    float* partials = (float*)((char*)d_ws + 64);     // 256 x 64KB partials

    hipMemsetAsync(d_ws, 0, 64, stream);              // zero the total only

    kde_hist_kernel<<<NBLK, TPB, 0, stream>>>(x, ex, ey, ws_total, partials, n);
    kde_final_kernel<<<NB2 / 64, TPB2, 0, stream>>>(partials, ws_total, ex, ey, out);
}

// Round 6
// 155.593 us; speedup vs baseline: 2.2205x; 1.8434x over previous
//
#include <hip/hip_runtime.h>

#define NBINS   128
#define NB2     (NBINS * NBINS)
#define TPB     256
#define NBLK    256
#define KC      64
#define TPB2    256

typedef __attribute__((ext_vector_type(8)))  short  short8;
typedef __attribute__((ext_vector_type(16))) float  f32x16;

// fp32 -> bf16 bits, round-nearest-even (no NaN inputs here)
__device__ __forceinline__ unsigned short f2bf(float f) {
    unsigned u = __float_as_uint(f);
    return (unsigned short)((u + 0x7FFFu + ((u >> 16) & 1u)) >> 16);
}

// Kernel 1: hist = kx^T * ky as a 128x128xK bf16 MFMA GEMM (dense taps, no
// truncation). R3-R5 proved scattered LDS fp32 atomics run at ~3.3 cyc/lane
// (structural); MFMA converts the contraction to the matrix pipe.
// Per block: 4 waves, each owns a 64x64 quadrant = 2x2 tiles of 32x32.
// A/B fragments are GENERATED in registers from broadcast u/v values:
//   A[m][k] = exp(-0.5 (u_k - m)^2), lane layout m=lane&31, k=(lane>>5)*8+j
//   B[k][n] = exp(-0.5 (v_k - n)^2), lane layout n=lane&31, k=(lane>>5)*8+j
// so LDS holds only u/v (2x64 floats, ping-pong, broadcast reads).
__global__ __launch_bounds__(TPB) void kde_mfma_kernel(
    const float* __restrict__ x,
    const float* __restrict__ ex,
    const float* __restrict__ ey,
    float* __restrict__ partials,
    int n, int nchunks)
{
    __shared__ __align__(16) float u_s[2][KC];
    __shared__ __align__(16) float v_s[2][KC];

    const int tid  = (int)threadIdx.x;
    const int lane = tid & 63;
    const int half = lane >> 5;      // k-half within a 16-k step
    const int l31  = lane & 31;
    const int wave = tid >> 6;
    const int rowblk = (wave >> 1) * 64;   // quadrant rows
    const int colblk = (wave & 1) * 64;    // quadrant cols
    const float rowf = (float)(rowblk + l31);
    const float colf = (float)(colblk + l31);

    const float lox = ex[0], loy = ey[0];
    const float ibx = 1.0f / (ex[1] - ex[0]);
    const float iby = 1.0f / (ey[1] - ey[0]);

    f32x16 acc[2][2];
    #pragma unroll
    for (int a = 0; a < 2; ++a)
        #pragma unroll
        for (int c = 0; c < 2; ++c)
            #pragma unroll
            for (int r = 0; r < 16; ++r) acc[a][c][r] = 0.f;

    // stage chunk t's u/v into buffer bb (first wave only); u = (x-lo)/bw-0.5
    // so tap at bin i is exp(-0.5 (u-i)^2); pad points get u=1e9 -> weight 0
    auto stage = [&](int t, int bb) {
        if (tid < KC) {
            const int p = t * KC + tid;
            float uu = 1e9f, vv = 1e9f;
            if (p < n) {
                const float2 xy = *(const float2*)(x + (size_t)p * 6);
                uu = (xy.x - lox) * ibx - 0.5f;
                vv = (xy.y - loy) * iby - 0.5f;
            }
            u_s[bb][tid] = uu; v_s[bb][tid] = vv;
        }
    };

    int t = (int)blockIdx.x;
    if (t < nchunks) stage(t, 0);
    int ci = 0;
    for (; t < nchunks; t += NBLK, ++ci) {
        __syncthreads();
        const int tn = t + NBLK;
        if (tn < nchunks) stage(tn, (ci + 1) & 1);
        const int bb = ci & 1;

        #pragma unroll
        for (int s = 0; s < 4; ++s) {          // 4 k-steps of 16 points
            const int kb = s * 16 + half * 8;
            const float4 ua = *(const float4*)&u_s[bb][kb];
            const float4 ub = *(const float4*)&u_s[bb][kb + 4];
            const float4 va = *(const float4*)&v_s[bb][kb];
            const float4 vb = *(const float4*)&v_s[bb][kb + 4];
            const float uu[8] = {ua.x, ua.y, ua.z, ua.w, ub.x, ub.y, ub.z, ub.w};
            const float vv[8] = {va.x, va.y, va.z, va.w, vb.x, vb.y, vb.z, vb.w};

            short8 af[2], bf[2];
            #pragma unroll
            for (int rb = 0; rb < 2; ++rb) {
                const float m = rowf + (float)(rb * 32);
                #pragma unroll
                for (int j = 0; j < 8; ++j) {
                    const float d = uu[j] - m;
                    af[rb][j] = (short)f2bf(__expf(-0.5f * d * d));
                }
            }
            #pragma unroll
            for (int tj = 0; tj < 2; ++tj) {
                const float c = colf + (float)(tj * 32);
                #pragma unroll
                for (int j = 0; j < 8; ++j) {
                    const float d = vv[j] - c;
                    bf[tj][j] = (short)f2bf(__expf(-0.5f * d * d));
                }
            }
            #pragma unroll
            for (int rb = 0; rb < 2; ++rb)
                #pragma unroll
                for (int tj = 0; tj < 2; ++tj)
                    acc[rb][tj] = __builtin_amdgcn_mfma_f32_32x32x16_bf16(
                        af[rb], bf[tj], acc[rb][tj], 0, 0, 0);
        }
    }

    // writeback: C/D layout col=lane&31, row=(reg&3)+8*(reg>>2)+4*(lane>>5).
    // Row-rotate each slot by blockIdx (+512B) to spread L2 sets across the
    // 64KB-strided slots (suspected cause of R5's slow reduce).
    const unsigned rot = (unsigned)blockIdx.x * NBINS;
    float* dst = partials + (size_t)blockIdx.x * NB2;
    #pragma unroll
    for (int rb = 0; rb < 2; ++rb)
        #pragma unroll
        for (int tj = 0; tj < 2; ++tj)
            #pragma unroll
            for (int r = 0; r < 16; ++r) {
                const int row = rowblk + rb * 32 + (r & 3) + 8 * (r >> 2) + 4 * half;
                const int col = colblk + tj * 32 + l31;
                const unsigned lin = ((unsigned)(row * NBINS + col) + rot) & (NB2 - 1);
                dst[lin] = acc[rb][tj][r];
            }
}

// Kernel 2: reduce 256 rotated slots -> unnormalized hist in out; also
// accumulate the grand total (one device atomic per block).
__global__ __launch_bounds__(TPB2) void kde_reduce_kernel(
    const float* __restrict__ partials,
    float* __restrict__ out,
    float* __restrict__ ws_total)
{
    __shared__ float red[TPB2];
    const int lane = (int)threadIdx.x & 63;
    const int g    = (int)threadIdx.x >> 6;
    const int bin  = (int)blockIdx.x * 64 + lane;

    float a = 0.f;
    #pragma unroll 8
    for (int p = g * 64; p < g * 64 + 64; ++p) {
        const unsigned lin = ((unsigned)bin + (unsigned)p * NBINS) & (NB2 - 1);
        a += partials[(size_t)p * NB2 + lin];
    }
    red[threadIdx.x] = a;
    __syncthreads();

    if (threadIdx.x < 64) {
        const float tot = red[lane] + red[64 + lane] +
                          red[128 + lane] + red[192 + lane];
        out[bin] = tot;
        float s = tot;
        #pragma unroll
        for (int off = 32; off > 0; off >>= 1) s += __shfl_down(s, off, 64);
        if (lane == 0) unsafeAtomicAdd(ws_total, s);
    }
}

// Kernel 3: normalize in place (total is self-consistent: sum of the hist
// actually computed, so bf16 quantization bias cancels in the ratio).
__global__ __launch_bounds__(TPB2) void kde_norm_kernel(
    float* __restrict__ out,
    const float* __restrict__ ws_total,
    const float* __restrict__ ex,
    const float* __restrict__ ey)
{
    const int i = (int)blockIdx.x * TPB2 + (int)threadIdx.x;
    const float bwx = ex[1] - ex[0];
    const float bwy = ey[1] - ey[0];
    const float inv = 1.0f / (ws_total[0] * bwx * bwy);
    out[i] *= inv;
}

extern "C" void kernel_launch(void* const* d_in, const int* in_sizes, int n_in,
                              void* d_out, int out_size, void* d_ws, size_t ws_size,
                              hipStream_t stream)
{
    const float* x  = (const float*)d_in[0];
    const float* ex = (const float*)d_in[1];
    const float* ey = (const float*)d_in[2];
    float* out = (float*)d_out;
    const int n = in_sizes[0] / 6;
    const int nchunks = (n + KC - 1) / KC;

    float* ws_total = (float*)d_ws;                   // ws[0]: grand total
    float* partials = (float*)((char*)d_ws + 64);     // 256 x 64KB (proven fit)

    hipMemsetAsync(d_ws, 0, 64, stream);              // zero the total only

    kde_mfma_kernel<<<NBLK, TPB, 0, stream>>>(x, ex, ey, partials, n, nchunks);
    kde_reduce_kernel<<<NB2 / 64, TPB2, 0, stream>>>(partials, out, ws_total);
    kde_norm_kernel<<<NB2 / TPB2, TPB2, 0, stream>>>(out, ws_total, ex, ey);
}

// Round 7
// 126.404 us; speedup vs baseline: 2.7333x; 1.2309x over previous
//
#include <hip/hip_runtime.h>

#define NBINS 128
#define NB2   (NBINS * NBINS)
#define TPB   1024            // 16 waves = 4 teams x 4 quadrant-waves
#define NBLK  256             // 1 block/CU
#define KC    64              // points per chunk
#define NTEAM 4

typedef __attribute__((ext_vector_type(8)))  short short8;
typedef __attribute__((ext_vector_type(16))) float f32x16;

// native 2^x (v_exp_f32); inputs here are <= 0 and finite
__device__ __forceinline__ float exp2_fast(float x) {
#if defined(__has_builtin)
#if __has_builtin(__builtin_amdgcn_exp2f)
    return __builtin_amdgcn_exp2f(x);
#else
    return exp2f(x);
#endif
#else
    return exp2f(x);
#endif
}

// pack two fp32 -> two bf16 (round-half-up, <=0.5ulp) in one v_perm:
// result = [bf16(b) : bf16(a)]
__device__ __forceinline__ unsigned pk_bf16(float a, float b) {
    const unsigned ar = __float_as_uint(a) + 0x8000u;
    const unsigned br = __float_as_uint(b) + 0x8000u;
    // v_perm_b32: sel codes 0-3 pick src1 bytes, 4-7 pick src0 bytes
    return __builtin_amdgcn_perm(br, ar, 0x07060302u);  // [b.b3 b.b2 a.b3 a.b2]
}

// C = -0.5 * log2(e): weight(d) = exp(-0.5 d^2) = exp2(C d^2)
#define WC (-0.72134752044448170f)

union S8 { short8 s; unsigned u[4]; };

// Kernel 1: hist = kx^T * ky as 128x128xK bf16 MFMA GEMM, dense taps.
// 4 teams x 4 waves; team handles chunk g = blk*4+team + it*1024; wave owns a
// 64x64 quadrant (2x2 tiles of 32x32). Fragments generated in registers from
// LDS-broadcast u/v. End: 4-pass LDS merge (plain ds ops -- LDS *atomics*
// measured 3.3cyc/lane in R3-R5, avoid), then global atomic add into out.
__global__ __launch_bounds__(TPB, 4) void kde_mfma_kernel(
    const float* __restrict__ x,
    const float* __restrict__ ex,
    const float* __restrict__ ey,
    float* __restrict__ out,
    int n, int nchunks)
{
    __shared__ float hist[NB2];                      // 64 KB merge buffer
    __shared__ __align__(16) float u_s[2][NTEAM][KC];
    __shared__ __align__(16) float v_s[2][NTEAM][KC];

    const int tid  = (int)threadIdx.x;
    const int lane = tid & 63;
    const int half = lane >> 5;          // k-half of a 16-k step
    const int l31  = lane & 31;
    const int w4   = (tid >> 6) & 3;     // wave within team
    const int team = tid >> 8;           // 0..3
    const int rowblk = (w4 >> 1) * 64;
    const int colblk = (w4 & 1) * 64;
    const float rowf = (float)(rowblk + l31);
    const float colf = (float)(colblk + l31);

    const float lox = ex[0], loy = ey[0];
    const float ibx = 1.0f / (ex[1] - ex[0]);
    const float iby = 1.0f / (ey[1] - ey[0]);

    f32x16 acc[2][2];
    #pragma unroll
    for (int a = 0; a < 2; ++a)
        #pragma unroll
        for (int c = 0; c < 2; ++c)
            #pragma unroll
            for (int r = 0; r < 16; ++r) acc[a][c][r] = 0.f;

    // stage iteration it into buffer bb: threads 0..255, one point each;
    // u = (x-lo)/bw - 0.5 so tap i has d = u - i; pad u=1e9 -> weight 0
    auto stage = [&](int it, int bb) {
        if (tid < NTEAM * KC) {
            const int tm  = tid >> 6, idx = tid & 63;
            const int g   = (int)blockIdx.x * NTEAM + tm + it * (NBLK * NTEAM);
            if (g < nchunks) {
                const int p = g * KC + idx;
                float uu = 1e9f, vv = 1e9f;
                if (p < n) {
                    const float2 xy = *(const float2*)(x + (size_t)p * 6);
                    uu = (xy.x - lox) * ibx - 0.5f;
                    vv = (xy.y - loy) * iby - 0.5f;
                }
                u_s[bb][tm][idx] = uu; v_s[bb][tm][idx] = vv;
            }
        }
    };

    const int niter = (nchunks + NBLK * NTEAM - 1) / (NBLK * NTEAM);
    stage(0, 0);
    for (int it = 0; it < niter; ++it) {
        __syncthreads();                          // staged data visible
        if (it + 1 < niter) stage(it + 1, (it + 1) & 1);
        const int bb = it & 1;
        const int g = (int)blockIdx.x * NTEAM + team + it * (NBLK * NTEAM);
        if (g < nchunks) {
            const float* us = u_s[bb][team];
            const float* vs = v_s[bb][team];
            #pragma unroll
            for (int s4 = 0; s4 < 4; ++s4) {      // 4 k-steps of 16 points
                const int kb = s4 * 16 + half * 8;
                const float4 ua = *(const float4*)&us[kb];
                const float4 ub = *(const float4*)&us[kb + 4];
                const float4 va = *(const float4*)&vs[kb];
                const float4 vb = *(const float4*)&vs[kb + 4];

                S8 af[2], bf[2];
                #pragma unroll
                for (int rb = 0; rb < 2; ++rb) {
                    const float m = rowf + (float)(rb * 32);
                    float d0 = ua.x - m, d1 = ua.y - m, d2 = ua.z - m, d3 = ua.w - m;
                    float d4 = ub.x - m, d5 = ub.y - m, d6 = ub.z - m, d7 = ub.w - m;
                    const float w0 = exp2_fast((WC * d0) * d0);
                    const float w1 = exp2_fast((WC * d1) * d1);
                    const float w2 = exp2_fast((WC * d2) * d2);
                    const float w3 = exp2_fast((WC * d3) * d3);
                    const float w4f = exp2_fast((WC * d4) * d4);
                    const float w5 = exp2_fast((WC * d5) * d5);
                    const float w6 = exp2_fast((WC * d6) * d6);
                    const float w7 = exp2_fast((WC * d7) * d7);
                    af[rb].u[0] = pk_bf16(w0, w1);
                    af[rb].u[1] = pk_bf16(w2, w3);
                    af[rb].u[2] = pk_bf16(w4f, w5);
                    af[rb].u[3] = pk_bf16(w6, w7);
                }
                #pragma unroll
                for (int tj = 0; tj < 2; ++tj) {
                    const float c = colf + (float)(tj * 32);
                    float d0 = va.x - c, d1 = va.y - c, d2 = va.z - c, d3 = va.w - c;
                    float d4 = vb.x - c, d5 = vb.y - c, d6 = vb.z - c, d7 = vb.w - c;
                    const float w0 = exp2_fast((WC * d0) * d0);
                    const float w1 = exp2_fast((WC * d1) * d1);
                    const float w2 = exp2_fast((WC * d2) * d2);
                    const float w3 = exp2_fast((WC * d3) * d3);
                    const float w4f = exp2_fast((WC * d4) * d4);
                    const float w5 = exp2_fast((WC * d5) * d5);
                    const float w6 = exp2_fast((WC * d6) * d6);
                    const float w7 = exp2_fast((WC * d7) * d7);
                    bf[tj].u[0] = pk_bf16(w0, w1);
                    bf[tj].u[1] = pk_bf16(w2, w3);
                    bf[tj].u[2] = pk_bf16(w4f, w5);
                    bf[tj].u[3] = pk_bf16(w6, w7);
                }
                #pragma unroll
                for (int rb = 0; rb < 2; ++rb)
                    #pragma unroll
                    for (int tj = 0; tj < 2; ++tj)
                        acc[rb][tj] = __builtin_amdgcn_mfma_f32_32x32x16_bf16(
                            af[rb].s, bf[tj].s, acc[rb][tj], 0, 0, 0);
            }
        }
    }
    __syncthreads();

    // merge teams into LDS hist: 4 barrier-ordered passes of plain ds ops.
    // C/D layout (verified R6): row=(r&3)+8*(r>>2)+4*half, col=l31 per tile.
    for (int tm = 0; tm < NTEAM; ++tm) {
        if (team == tm) {
            #pragma unroll
            for (int rb = 0; rb < 2; ++rb)
                #pragma unroll
                for (int tj = 0; tj < 2; ++tj)
                    #pragma unroll
                    for (int r = 0; r < 16; ++r) {
                        const int row = rowblk + rb * 32 + (r & 3) + 8 * (r >> 2) + 4 * half;
                        const int col = colblk + tj * 32 + l31;
                        const int a = row * NBINS + col;
                        const float v = acc[rb][tj][r];
                        if (tm == 0) hist[a] = v;
                        else         hist[a] += v;
                    }
        }
        __syncthreads();
    }

    // device-scope atomic merge into out (zeroed host-side); 64KB target
    // stays L2/L3-resident; 256 wave-atomics per block
    for (int i = tid; i < NB2; i += TPB)
        unsafeAtomicAdd(&out[i], hist[i]);
}

// Kernel 2 (fused finalize): single block; total-reduce in registers,
// normalize in place. Replaces the persistently slow slot-reduce pipeline.
__global__ __launch_bounds__(TPB) void kde_final_kernel(
    float* __restrict__ out,
    const float* __restrict__ ex,
    const float* __restrict__ ey)
{
    __shared__ float red[TPB / 64];
    __shared__ float sinv;
    const int tid = (int)threadIdx.x;

    float4 v[4];
    float s = 0.f;
    #pragma unroll
    for (int i = 0; i < 4; ++i) {
        v[i] = ((const float4*)out)[tid + i * TPB];
        s += v[i].x + v[i].y + v[i].z + v[i].w;
    }
    #pragma unroll
    for (int off = 32; off > 0; off >>= 1) s += __shfl_down(s, off, 64);
    if ((tid & 63) == 0) red[tid >> 6] = s;
    __syncthreads();
    if (tid == 0) {
        float t = 0.f;
        #pragma unroll
        for (int i = 0; i < TPB / 64; ++i) t += red[i];
        sinv = 1.0f / (t * (ex[1] - ex[0]) * (ey[1] - ey[0]));
    }
    __syncthreads();
    const float inv = sinv;
    #pragma unroll
    for (int i = 0; i < 4; ++i) {
        float4 o = v[i];
        o.x *= inv; o.y *= inv; o.z *= inv; o.w *= inv;
        ((float4*)out)[tid + i * TPB] = o;
    }
}

extern "C" void kernel_launch(void* const* d_in, const int* in_sizes, int n_in,
                              void* d_out, int out_size, void* d_ws, size_t ws_size,
                              hipStream_t stream)
{
    const float* x  = (const float*)d_in[0];
    const float* ex = (const float*)d_in[1];
    const float* ey = (const float*)d_in[2];
    float* out = (float*)d_out;
    const int n = in_sizes[0] / 6;
    const int nchunks = (n + KC - 1) / KC;

    hipMemsetAsync(d_out, 0, NB2 * sizeof(float), stream);  // atomic target
    kde_mfma_kernel<<<NBLK, TPB, 0, stream>>>(x, ex, ey, out, n, nchunks);
    kde_final_kernel<<<1, TPB, 0, stream>>>(out, ex, ey);
}